// Round 21
// baseline (72.135 us; speedup 1.0000x reference)
//
#include <hip/hip_runtime.h>
#include <math.h>

#define B_ 8
#define N_ 4096
// (1/sqrt(7)) * log2(e): Q pre-scale so logits are in base-2 domain (exp2 softmax)
#define SCALE2_ 0.54528747f

typedef __bf16 bf16x8 __attribute__((ext_vector_type(8)));
typedef float f32x4 __attribute__((ext_vector_type(4)));
typedef float f32x16 __attribute__((ext_vector_type(16)));
typedef unsigned short ushortx8 __attribute__((ext_vector_type(8)));
typedef unsigned short ushort;
typedef unsigned int uint;
typedef uint uint2v __attribute__((ext_vector_type(2)));

static __device__ __forceinline__ ushort f2bf(float f) {
  union { float f; unsigned u; } v; v.f = f;
  unsigned r = v.u + 0x7FFFu + ((v.u >> 16) & 1u);  // RNE
  return (ushort)(r >> 16);
}
static __device__ __forceinline__ float bf2f(ushort h) {
  union { unsigned u; float f; } v; v.u = ((unsigned)h) << 16;
  return v.f;
}
static __device__ __forceinline__ uint pk2(float a, float b) {
  union { __bf16 h[2]; uint u; } v;
  v.h[0] = (__bf16)a; v.h[1] = (__bf16)b;
  return v.u;
}

// ---------------------------------------------------------------------------
// Kernel 1: MFMA-based projections (R20-proven, unchanged: 80.5->72.0us,
// absmax identical). Grid (256 pixel-blocks, 3 mats), 4 waves x 32 pixels.
// x -> bf16 hi/lo B-frags; W -> lane-mapped bf16 frags; 16 MFMAs; bias;
// pk2+permlane32_swap EXCH -> 16B coalesced stores into flash's layouts:
//   Qb row-major [b][n][64] (Q pre-scaled by SCALE2_)
//   KF[b][kvblk][ks(4)][h(2)][r32(32)][8]
//   VF[b][kvblk][ks2(2)][h(2)][o(64)][8]
// ---------------------------------------------------------------------------
__global__ __launch_bounds__(256)
void proj_kernel(const float* __restrict__ x,
                 const float* __restrict__ Wq, const float* __restrict__ bq,
                 const float* __restrict__ Wk, const float* __restrict__ bk,
                 const float* __restrict__ Wv, const float* __restrict__ bv,
                 ushort* __restrict__ Qb, ushort* __restrict__ KF,
                 ushort* __restrict__ VF)
{
  const int tid  = threadIdx.x;
  const int lane = tid & 63;
  const int w    = tid >> 6;       // wave = 32-pixel group
  const int r32  = lane & 31;
  const int h2   = lane >> 5;
  const int mat  = blockIdx.y;     // 0=Q 1=K 2=V

  const int gp0 = blockIdx.x << 7;         // block's 128-pixel base
  const int b   = gp0 >> 12;
  const int nb  = gp0 & 4095;
  const int n   = nb + (w << 5) + r32;     // this lane's pixel

  const float* W    = (mat == 0) ? Wq : (mat == 1) ? Wk : Wv;
  const float* bias = (mat == 0) ? bq : (mat == 1) ? bk : bv;
  const float  scl  = (mat == 0) ? SCALE2_ : 1.0f;

  // ---- x fragments, hi/lo split: lane (pixel=r32, h2) holds c=16ks+8h2+j ----
  bf16x8 xh[4], xl[4];
  #pragma unroll
  for (int ks = 0; ks < 4; ++ks) {
    union { ushort u[8]; bf16x8 v; } th, tl;
    #pragma unroll
    for (int j = 0; j < 8; ++j) {
      const int c = (ks << 4) + (h2 << 3) + j;
      float val = x[((size_t)b << 18) + ((size_t)c << 12) + n];
      ushort hv = f2bf(val);
      th.u[j] = hv;
      tl.u[j] = f2bf(val - bf2f(hv));
    }
    xh[ks] = th.v;
    xl[ks] = tl.v;
  }

  // ---- W fragments: lane o = 32t+r32 holds W[o][c=16ks+8h2+j] (scaled) ----
  bf16x8 wf[2][4];
  #pragma unroll
  for (int t = 0; t < 2; ++t) {
    #pragma unroll
    for (int ks = 0; ks < 4; ++ks) {
      const float* wp = W + (((t << 5) + r32) << 6) + (ks << 4) + (h2 << 3);
      float4 a  = *(const float4*)wp;
      float4 c4 = *(const float4*)(wp + 4);
      union { ushort u[8]; bf16x8 v; } tw;
      tw.u[0] = f2bf(a.x * scl);  tw.u[1] = f2bf(a.y * scl);
      tw.u[2] = f2bf(a.z * scl);  tw.u[3] = f2bf(a.w * scl);
      tw.u[4] = f2bf(c4.x * scl); tw.u[5] = f2bf(c4.y * scl);
      tw.u[6] = f2bf(c4.z * scl); tw.u[7] = f2bf(c4.w * scl);
      wf[t][ks] = tw.v;
    }
  }

  const f32x16 Z = (f32x16)(0.0f);
  const size_t rowb = (((size_t)b << 12) + n) << 6;                 // Qb row
  const size_t kfb  = ((size_t)(b * 128 + (nb >> 5) + w)) * 2048;   // K/V blk

  #pragma unroll
  for (int t = 0; t < 2; ++t) {
    f32x16 Dh = Z, Dl = Z;
    if (mat == 2) {
      #pragma unroll
      for (int ks = 0; ks < 4; ++ks) {
        Dh = __builtin_amdgcn_mfma_f32_32x32x16_bf16(xh[ks], wf[t][ks], Dh, 0, 0, 0);
        Dl = __builtin_amdgcn_mfma_f32_32x32x16_bf16(xl[ks], wf[t][ks], Dl, 0, 0, 0);
      }
    } else {
      #pragma unroll
      for (int ks = 0; ks < 4; ++ks) {
        Dh = __builtin_amdgcn_mfma_f32_32x32x16_bf16(wf[t][ks], xh[ks], Dh, 0, 0, 0);
        Dl = __builtin_amdgcn_mfma_f32_32x32x16_bf16(wf[t][ks], xl[ks], Dl, 0, 0, 0);
      }
    }

    f32x16 D;
    if (mat == 2) {
      const float bvl = bias[(t << 5) + r32];
      #pragma unroll
      for (int i = 0; i < 16; ++i) D[i] = Dh[i] + Dl[i] + bvl;
    } else {
      float bm[16];
      #pragma unroll
      for (int g2 = 0; g2 < 4; ++g2) {
        float4 t4 = *(const float4*)(bias + (t << 5) + (g2 << 3) + (h2 << 2));
        bm[4*g2+0] = t4.x * scl; bm[4*g2+1] = t4.y * scl;
        bm[4*g2+2] = t4.z * scl; bm[4*g2+3] = t4.w * scl;
      }
      #pragma unroll
      for (int i = 0; i < 16; ++i) D[i] = Dh[i] + Dl[i] + bm[i];
    }

    #pragma unroll
    for (int g = 0; g < 2; ++g) {
      uint plo0 = pk2(D[8*g+0], D[8*g+1]);
      uint plo1 = pk2(D[8*g+2], D[8*g+3]);
      uint phi0 = pk2(D[8*g+4], D[8*g+5]);
      uint phi1 = pk2(D[8*g+6], D[8*g+7]);
      uint2v r0 = __builtin_amdgcn_permlane32_swap(plo0, phi0, false, false);
      uint2v r1 = __builtin_amdgcn_permlane32_swap(plo1, phi1, false, false);
      union { uint u[4]; ushortx8 v8; } ch;
      ch.u[0] = r0.x; ch.u[1] = r1.x; ch.u[2] = r0.y; ch.u[3] = r1.y;
      if (mat == 0) {
        *(ushortx8*)(Qb + rowb + (t << 5) + (g << 4) + (h2 << 3)) = ch.v8;
      } else if (mat == 1) {
        *(ushortx8*)(KF + kfb + ((2*t + g) << 9) + (h2 << 8) + (r32 << 3)) = ch.v8;
      } else {
        *(ushortx8*)(VF + kfb + (g << 10) + (h2 << 9) + (((t << 5) + r32) << 3)) = ch.v8;
      }
    }
  }
}

// ---------------------------------------------------------------------------
// Kernel 2: flash attention, fragment-direct + 64q reuse (R16/R19/R20 base)
// with the TWO q-TILES HAND-INTERLEAVED per stage. Prior rounds proved the
// wall (64us across 6 variants) is not occupancy (R14), not L2 BW (R16),
// not load prefetch (R15/R17). Untested mechanism: intra-wave ILP across
// the independent A/B tiles -- S-MFMA chains, exp2, EXCH, and PV chains
// alternate A/B so the SIMD always has a second independent chain to issue
// from, halving exposed dependency latency. Pure reorder of independent FP
// ops: per-tile accumulation order unchanged -> bit-identical output.
// ---------------------------------------------------------------------------
__global__ __launch_bounds__(256, 2)
void flash_kernel(const ushort* __restrict__ Qb, const ushort* __restrict__ KF,
                  const ushort* __restrict__ VF, float* __restrict__ out)
{
  __shared__ float cmb[3][64][66];   // 50688 B, end merge only

  const int tid  = threadIdx.x;
  const int lane = tid & 63;
  const int w    = tid >> 6;       // kv-quarter 0..3
  const int r32  = lane & 31;
  const int h    = lane >> 5;      // 0..1
  const int h8   = h << 3;

  // 512 blocks = 8 XCD x 64; XCD owns one batch (K/V L2-resident)
  const int bidx = (blockIdx.x & 7) * 64 + (blockIdx.x >> 3);
  const int b  = bidx >> 6;
  const int qw = (bidx & 63) << 6;            // block's 64-q window

  // Q B-frags for BOTH 32-q tiles: col(q)=lane&31, k(c)=16ks+8h+j
  bf16x8 qfA[4], qfB[4];
  {
    const ushort* qa = Qb + ((((size_t)b << 12) + qw + r32) << 6) + h8;
    const ushort* qb2 = Qb + ((((size_t)b << 12) + qw + 32 + r32) << 6) + h8;
    #pragma unroll
    for (int ks = 0; ks < 4; ++ks) {
      qfA[ks] = *(const bf16x8*)(qa + (ks << 4));
      qfB[ks] = *(const bf16x8*)(qb2 + (ks << 4));
    }
  }

  const ushort* kb = KF + ((size_t)((b << 7) + (w << 5))) * 2048 + (lane << 3);
  const ushort* vb = VF + ((size_t)((b << 7) + (w << 5))) * 2048 + (h << 9) + (r32 << 3);

  const f32x16 Z = (f32x16)(0.0f);
  f32x16 accA0 = Z, accA1 = Z, accB0 = Z, accB1 = Z;
  float lA = 0.f, lB = 0.f;

  #define EXCH(SV, c, DST) do { \
    uint plo0 = pk2(SV[8*(c)+0], SV[8*(c)+1]); \
    uint plo1 = pk2(SV[8*(c)+2], SV[8*(c)+3]); \
    uint phi0 = pk2(SV[8*(c)+4], SV[8*(c)+5]); \
    uint phi1 = pk2(SV[8*(c)+6], SV[8*(c)+7]); \
    uint2v r0 = __builtin_amdgcn_permlane32_swap(plo0, phi0, false, false); \
    uint2v r1 = __builtin_amdgcn_permlane32_swap(plo1, phi1, false, false); \
    union { uint u[4]; bf16x8 v; } f_; \
    f_.u[0] = r0.x; f_.u[1] = r1.x; f_.u[2] = r0.y; f_.u[3] = r1.y; \
    DST = f_.v; \
  } while (0)

  #pragma unroll 1
  for (int t = 0; t < 32; ++t) {
    // ---- 8 coalesced fragment loads, shared by BOTH q-tiles ----
    bf16x8 k0 = *(const bf16x8*)(kb);
    bf16x8 k1 = *(const bf16x8*)(kb + 512);
    bf16x8 k2 = *(const bf16x8*)(kb + 1024);
    bf16x8 k3 = *(const bf16x8*)(kb + 1536);
    bf16x8 v0 = *(const bf16x8*)(vb);
    bf16x8 v1 = *(const bf16x8*)(vb + 256);
    bf16x8 v2 = *(const bf16x8*)(vb + 1024);
    bf16x8 v3 = *(const bf16x8*)(vb + 1280);
    kb += 2048; vb += 2048;

    // ---- S phase: A/B chains interleaved (2 independent MFMA chains) ----
    __builtin_amdgcn_s_setprio(1);
    f32x16 sA = __builtin_amdgcn_mfma_f32_32x32x16_bf16(k0, qfA[0], Z, 0, 0, 0);
    f32x16 sB = __builtin_amdgcn_mfma_f32_32x32x16_bf16(k0, qfB[0], Z, 0, 0, 0);
    sA = __builtin_amdgcn_mfma_f32_32x32x16_bf16(k1, qfA[1], sA, 0, 0, 0);
    sB = __builtin_amdgcn_mfma_f32_32x32x16_bf16(k1, qfB[1], sB, 0, 0, 0);
    sA = __builtin_amdgcn_mfma_f32_32x32x16_bf16(k2, qfA[2], sA, 0, 0, 0);
    sB = __builtin_amdgcn_mfma_f32_32x32x16_bf16(k2, qfB[2], sB, 0, 0, 0);
    sA = __builtin_amdgcn_mfma_f32_32x32x16_bf16(k3, qfA[3], sA, 0, 0, 0);
    sB = __builtin_amdgcn_mfma_f32_32x32x16_bf16(k3, qfB[3], sB, 0, 0, 0);
    __builtin_amdgcn_s_setprio(0);

    // ---- softmax phase: A/B exp2 interleaved ----
    float rsA = 0.f, rsB = 0.f;
    #pragma unroll
    for (int ii = 0; ii < 16; ++ii) {
      float pA = __builtin_exp2f(sA[ii]); sA[ii] = pA; rsA += pA;
      float pB = __builtin_exp2f(sB[ii]); sB[ii] = pB; rsB += pB;
    }
    lA += rsA; lB += rsB;

    // ---- pack/EXCH phase ----
    bf16x8 pbA0, pbA1, pbB0, pbB1;
    EXCH(sA, 0, pbA0);
    EXCH(sB, 0, pbB0);
    EXCH(sA, 1, pbA1);
    EXCH(sB, 1, pbB1);

    // ---- PV phase: 4 independent 2-deep chains interleaved ----
    __builtin_amdgcn_s_setprio(1);
    accA0 = __builtin_amdgcn_mfma_f32_32x32x16_bf16(v0, pbA0, accA0, 0, 0, 0);
    accB0 = __builtin_amdgcn_mfma_f32_32x32x16_bf16(v0, pbB0, accB0, 0, 0, 0);
    accA1 = __builtin_amdgcn_mfma_f32_32x32x16_bf16(v1, pbA0, accA1, 0, 0, 0);
    accB1 = __builtin_amdgcn_mfma_f32_32x32x16_bf16(v1, pbB0, accB1, 0, 0, 0);
    accA0 = __builtin_amdgcn_mfma_f32_32x32x16_bf16(v2, pbA1, accA0, 0, 0, 0);
    accB0 = __builtin_amdgcn_mfma_f32_32x32x16_bf16(v2, pbB1, accB0, 0, 0, 0);
    accA1 = __builtin_amdgcn_mfma_f32_32x32x16_bf16(v3, pbA1, accA1, 0, 0, 0);
    accB1 = __builtin_amdgcn_mfma_f32_32x32x16_bf16(v3, pbB1, accB1, 0, 0, 0);
    __builtin_amdgcn_s_setprio(0);
  }
  #undef EXCH

  // ---- 4-way merge of kv-quarter partials (shared implicit m=0) ----
  float lAm = lA + __shfl_xor(lA, 32);
  float lBm = lB + __shfl_xor(lB, 32);

  if (w != 0) {
    float* p = &cmb[w - 1][lane][0];
    #pragma unroll
    for (int i = 0; i < 16; ++i) {
      p[i]      = accA0[i];
      p[16 + i] = accA1[i];
      p[32 + i] = accB0[i];
      p[48 + i] = accB1[i];
    }
    p[64] = lAm;
    p[65] = lBm;
  }
  __syncthreads();
  if (w == 0) {
    float lsA = lAm, lsB = lBm;
    #pragma unroll
    for (int q = 0; q < 3; ++q) { lsA += cmb[q][lane][64]; lsB += cmb[q][lane][65]; }
    const float invA = 1.0f / lsA;
    const float invB = 1.0f / lsB;
    const size_t rowA = (((size_t)b << 12) + qw + r32) << 6;
    const size_t rowB = (((size_t)b << 12) + qw + 32 + r32) << 6;
    #pragma unroll
    for (int g = 0; g < 4; ++g) {
      f32x4 oA, oB;
      #pragma unroll
      for (int i = 0; i < 4; ++i) {
        float vA0 = accA0[4*g + i], vB0 = accB0[4*g + i];
        #pragma unroll
        for (int q = 0; q < 3; ++q) {
          vA0 += cmb[q][lane][4*g + i];
          vB0 += cmb[q][lane][32 + 4*g + i];
        }
        oA[i] = vA0 * invA;
        oB[i] = vB0 * invB;
      }
      *(f32x4*)(out + rowA + (g << 3) + (h << 2)) = oA;
      *(f32x4*)(out + rowB + (g << 3) + (h << 2)) = oB;
    }
    #pragma unroll
    for (int g = 0; g < 4; ++g) {
      f32x4 oA, oB;
      #pragma unroll
      for (int i = 0; i < 4; ++i) {
        float vA1 = accA1[4*g + i], vB1 = accB1[4*g + i];
        #pragma unroll
        for (int q = 0; q < 3; ++q) {
          vA1 += cmb[q][lane][16 + 4*g + i];
          vB1 += cmb[q][lane][48 + 4*g + i];
        }
        oA[i] = vA1 * invA;
        oB[i] = vB1 * invB;
      }
      *(f32x4*)(out + rowA + 32 + (g << 3) + (h << 2)) = oA;
      *(f32x4*)(out + rowB + 32 + (g << 3) + (h << 2)) = oB;
    }
  }
}

extern "C" void kernel_launch(void* const* d_in, const int* in_sizes, int n_in,
                              void* d_out, int out_size, void* d_ws, size_t ws_size,
                              hipStream_t stream) {
  (void)in_sizes; (void)n_in; (void)out_size; (void)ws_size;
  const float* x  = (const float*)d_in[0];
  const float* Wq = (const float*)d_in[1];
  const float* bq = (const float*)d_in[2];
  const float* Wk = (const float*)d_in[3];
  const float* bk = (const float*)d_in[4];
  const float* Wv = (const float*)d_in[5];
  const float* bv = (const float*)d_in[6];
  float* out = (float*)d_out;

  const size_t SZ = (size_t)B_ * N_ * 64;          // 2,097,152 elems (4 MB)
  ushort* Qb = (ushort*)d_ws;
  ushort* KF = Qb + SZ;
  ushort* VF = KF + SZ;

  proj_kernel<<<dim3(256, 3), dim3(256), 0, stream>>>(x, Wq, bq, Wk, bk, Wv, bv,
                                                      Qb, KF, VF);
  flash_kernel<<<dim3(512), dim3(256), 0, stream>>>(Qb, KF, VF, out);
}

// Round 22
// 72.023 us; speedup vs baseline: 1.0016x; 1.0016x over previous
//
#include <hip/hip_runtime.h>
#include <math.h>

#define B_ 8
#define N_ 4096
// (1/sqrt(7)) * log2(e): Q pre-scale so logits are in base-2 domain (exp2 softmax)
#define SCALE2_ 0.54528747f

typedef __bf16 bf16x8 __attribute__((ext_vector_type(8)));
typedef float f32x4 __attribute__((ext_vector_type(4)));
typedef float f32x16 __attribute__((ext_vector_type(16)));
typedef unsigned short ushortx8 __attribute__((ext_vector_type(8)));
typedef unsigned short ushort;
typedef unsigned int uint;
typedef uint uint2v __attribute__((ext_vector_type(2)));

static __device__ __forceinline__ ushort f2bf(float f) {
  union { float f; unsigned u; } v; v.f = f;
  unsigned r = v.u + 0x7FFFu + ((v.u >> 16) & 1u);  // RNE
  return (ushort)(r >> 16);
}
static __device__ __forceinline__ float bf2f(ushort h) {
  union { unsigned u; float f; } v; v.u = ((unsigned)h) << 16;
  return v.f;
}
static __device__ __forceinline__ uint pk2(float a, float b) {
  union { __bf16 h[2]; uint u; } v;
  v.h[0] = (__bf16)a; v.h[1] = (__bf16)b;
  return v.u;
}

// ---------------------------------------------------------------------------
// FINAL CONFIGURATION (session best, R20: 71.99us total; 4.3x vs first
// correct kernel). proj = MFMA GEMM writing flash's exact fragment layouts;
// flash = fragment-direct-from-L2, 64q-per-wave K/V reuse, max-free exp2
// softmax, permlane32_swap EXCH, zero main-loop barriers.
//
// Kernel 1: MFMA projections. Grid (256 pixel-blocks, 3 mats), 4 waves x 32
// pixels. x -> bf16 hi/lo B-frags (2-term split); W -> lane-mapped bf16
// frags; 16 MFMAs; bias; pk2+permlane32_swap EXCH -> 16B coalesced stores:
//   Qb row-major [b][n][64] (Q pre-scaled by SCALE2_)
//   KF[b][kvblk][ks(4)][h(2)][r32(32)][8]
//   VF[b][kvblk][ks2(2)][h(2)][o(64)][8]
// ---------------------------------------------------------------------------
__global__ __launch_bounds__(256)
void proj_kernel(const float* __restrict__ x,
                 const float* __restrict__ Wq, const float* __restrict__ bq,
                 const float* __restrict__ Wk, const float* __restrict__ bk,
                 const float* __restrict__ Wv, const float* __restrict__ bv,
                 ushort* __restrict__ Qb, ushort* __restrict__ KF,
                 ushort* __restrict__ VF)
{
  const int tid  = threadIdx.x;
  const int lane = tid & 63;
  const int w    = tid >> 6;       // wave = 32-pixel group
  const int r32  = lane & 31;
  const int h2   = lane >> 5;
  const int mat  = blockIdx.y;     // 0=Q 1=K 2=V

  const int gp0 = blockIdx.x << 7;         // block's 128-pixel base
  const int b   = gp0 >> 12;
  const int nb  = gp0 & 4095;
  const int n   = nb + (w << 5) + r32;     // this lane's pixel

  const float* W    = (mat == 0) ? Wq : (mat == 1) ? Wk : Wv;
  const float* bias = (mat == 0) ? bq : (mat == 1) ? bk : bv;
  const float  scl  = (mat == 0) ? SCALE2_ : 1.0f;

  // ---- x fragments, hi/lo split: lane (pixel=r32, h2) holds c=16ks+8h2+j ----
  bf16x8 xh[4], xl[4];
  #pragma unroll
  for (int ks = 0; ks < 4; ++ks) {
    union { ushort u[8]; bf16x8 v; } th, tl;
    #pragma unroll
    for (int j = 0; j < 8; ++j) {
      const int c = (ks << 4) + (h2 << 3) + j;
      float val = x[((size_t)b << 18) + ((size_t)c << 12) + n];
      ushort hv = f2bf(val);
      th.u[j] = hv;
      tl.u[j] = f2bf(val - bf2f(hv));
    }
    xh[ks] = th.v;
    xl[ks] = tl.v;
  }

  // ---- W fragments: lane o = 32t+r32 holds W[o][c=16ks+8h2+j] (scaled) ----
  bf16x8 wf[2][4];
  #pragma unroll
  for (int t = 0; t < 2; ++t) {
    #pragma unroll
    for (int ks = 0; ks < 4; ++ks) {
      const float* wp = W + (((t << 5) + r32) << 6) + (ks << 4) + (h2 << 3);
      float4 a  = *(const float4*)wp;
      float4 c4 = *(const float4*)(wp + 4);
      union { ushort u[8]; bf16x8 v; } tw;
      tw.u[0] = f2bf(a.x * scl);  tw.u[1] = f2bf(a.y * scl);
      tw.u[2] = f2bf(a.z * scl);  tw.u[3] = f2bf(a.w * scl);
      tw.u[4] = f2bf(c4.x * scl); tw.u[5] = f2bf(c4.y * scl);
      tw.u[6] = f2bf(c4.z * scl); tw.u[7] = f2bf(c4.w * scl);
      wf[t][ks] = tw.v;
    }
  }

  const f32x16 Z = (f32x16)(0.0f);
  const size_t rowb = (((size_t)b << 12) + n) << 6;                 // Qb row
  const size_t kfb  = ((size_t)(b * 128 + (nb >> 5) + w)) * 2048;   // K/V blk

  #pragma unroll
  for (int t = 0; t < 2; ++t) {
    f32x16 Dh = Z, Dl = Z;
    if (mat == 2) {
      #pragma unroll
      for (int ks = 0; ks < 4; ++ks) {
        Dh = __builtin_amdgcn_mfma_f32_32x32x16_bf16(xh[ks], wf[t][ks], Dh, 0, 0, 0);
        Dl = __builtin_amdgcn_mfma_f32_32x32x16_bf16(xl[ks], wf[t][ks], Dl, 0, 0, 0);
      }
    } else {
      #pragma unroll
      for (int ks = 0; ks < 4; ++ks) {
        Dh = __builtin_amdgcn_mfma_f32_32x32x16_bf16(wf[t][ks], xh[ks], Dh, 0, 0, 0);
        Dl = __builtin_amdgcn_mfma_f32_32x32x16_bf16(wf[t][ks], xl[ks], Dl, 0, 0, 0);
      }
    }

    f32x16 D;
    if (mat == 2) {
      const float bvl = bias[(t << 5) + r32];
      #pragma unroll
      for (int i = 0; i < 16; ++i) D[i] = Dh[i] + Dl[i] + bvl;
    } else {
      float bm[16];
      #pragma unroll
      for (int g2 = 0; g2 < 4; ++g2) {
        float4 t4 = *(const float4*)(bias + (t << 5) + (g2 << 3) + (h2 << 2));
        bm[4*g2+0] = t4.x * scl; bm[4*g2+1] = t4.y * scl;
        bm[4*g2+2] = t4.z * scl; bm[4*g2+3] = t4.w * scl;
      }
      #pragma unroll
      for (int i = 0; i < 16; ++i) D[i] = Dh[i] + Dl[i] + bm[i];
    }

    #pragma unroll
    for (int g = 0; g < 2; ++g) {
      uint plo0 = pk2(D[8*g+0], D[8*g+1]);
      uint plo1 = pk2(D[8*g+2], D[8*g+3]);
      uint phi0 = pk2(D[8*g+4], D[8*g+5]);
      uint phi1 = pk2(D[8*g+6], D[8*g+7]);
      uint2v r0 = __builtin_amdgcn_permlane32_swap(plo0, phi0, false, false);
      uint2v r1 = __builtin_amdgcn_permlane32_swap(plo1, phi1, false, false);
      union { uint u[4]; ushortx8 v8; } ch;
      ch.u[0] = r0.x; ch.u[1] = r1.x; ch.u[2] = r0.y; ch.u[3] = r1.y;
      if (mat == 0) {
        *(ushortx8*)(Qb + rowb + (t << 5) + (g << 4) + (h2 << 3)) = ch.v8;
      } else if (mat == 1) {
        *(ushortx8*)(KF + kfb + ((2*t + g) << 9) + (h2 << 8) + (r32 << 3)) = ch.v8;
      } else {
        *(ushortx8*)(VF + kfb + (g << 10) + (h2 << 9) + (((t << 5) + r32) << 3)) = ch.v8;
      }
    }
  }
}

// ---------------------------------------------------------------------------
// Kernel 2: flash attention (measured-best). Fragment-direct from L2 +
// 64q-per-wave K/V reuse. 512 blocks = (b, 64q) x 4 waves (kv-quarters);
// zero main-loop barriers; max-free exp2 softmax (implicit m=0),
// permlane32_swap EXCH, 4-way LDS merge epilogue.
// ---------------------------------------------------------------------------
__global__ __launch_bounds__(256, 2)
void flash_kernel(const ushort* __restrict__ Qb, const ushort* __restrict__ KF,
                  const ushort* __restrict__ VF, float* __restrict__ out)
{
  __shared__ float cmb[3][64][66];   // 50688 B, end merge only

  const int tid  = threadIdx.x;
  const int lane = tid & 63;
  const int w    = tid >> 6;       // kv-quarter 0..3
  const int r32  = lane & 31;
  const int h    = lane >> 5;      // 0..1
  const int h8   = h << 3;

  // 512 blocks = 8 XCD x 64; XCD owns one batch (K/V L2-resident)
  const int bidx = (blockIdx.x & 7) * 64 + (blockIdx.x >> 3);
  const int b  = bidx >> 6;
  const int qw = (bidx & 63) << 6;            // block's 64-q window

  // Q B-frags for BOTH 32-q tiles: col(q)=lane&31, k(c)=16ks+8h+j
  bf16x8 qfA[4], qfB[4];
  {
    const ushort* qa = Qb + ((((size_t)b << 12) + qw + r32) << 6) + h8;
    const ushort* qb2 = Qb + ((((size_t)b << 12) + qw + 32 + r32) << 6) + h8;
    #pragma unroll
    for (int ks = 0; ks < 4; ++ks) {
      qfA[ks] = *(const bf16x8*)(qa + (ks << 4));
      qfB[ks] = *(const bf16x8*)(qb2 + (ks << 4));
    }
  }

  // fragment base pointers for this wave's kv-quarter (kvblk = w*32 + i)
  const ushort* kb = KF + ((size_t)((b << 7) + (w << 5))) * 2048 + (lane << 3);
  const ushort* vb = VF + ((size_t)((b << 7) + (w << 5))) * 2048 + (h << 9) + (r32 << 3);

  const f32x16 Z = (f32x16)(0.0f);
  f32x16 accA0 = Z, accA1 = Z, accB0 = Z, accB1 = Z;
  float lA = 0.f, lB = 0.f;

  // one 32q-tile's S->softmax->EXCH->PV against the already-loaded k/v regs
  #define TILE(QF, A0, A1, LV) do { \
    __builtin_amdgcn_s_setprio(1); \
    f32x16 s = __builtin_amdgcn_mfma_f32_32x32x16_bf16(k0, QF[0], Z, 0, 0, 0); \
    s = __builtin_amdgcn_mfma_f32_32x32x16_bf16(k1, QF[1], s, 0, 0, 0); \
    s = __builtin_amdgcn_mfma_f32_32x32x16_bf16(k2, QF[2], s, 0, 0, 0); \
    s = __builtin_amdgcn_mfma_f32_32x32x16_bf16(k3, QF[3], s, 0, 0, 0); \
    __builtin_amdgcn_s_setprio(0); \
    float rs = 0.f; \
    _Pragma("unroll") \
    for (int ii = 0; ii < 16; ++ii) { \
      float p = __builtin_exp2f(s[ii]); \
      s[ii] = p; \
      rs += p; \
    } \
    LV += rs; \
    bf16x8 pb0, pb1; \
    { \
      uint plo0 = pk2(s[0], s[1]); \
      uint plo1 = pk2(s[2], s[3]); \
      uint phi0 = pk2(s[4], s[5]); \
      uint phi1 = pk2(s[6], s[7]); \
      uint2v r0 = __builtin_amdgcn_permlane32_swap(plo0, phi0, false, false); \
      uint2v r1 = __builtin_amdgcn_permlane32_swap(plo1, phi1, false, false); \
      union { uint u[4]; bf16x8 v; } f_; \
      f_.u[0] = r0.x; f_.u[1] = r1.x; f_.u[2] = r0.y; f_.u[3] = r1.y; \
      pb0 = f_.v; \
    } \
    { \
      uint plo0 = pk2(s[8],  s[9]); \
      uint plo1 = pk2(s[10], s[11]); \
      uint phi0 = pk2(s[12], s[13]); \
      uint phi1 = pk2(s[14], s[15]); \
      uint2v r0 = __builtin_amdgcn_permlane32_swap(plo0, phi0, false, false); \
      uint2v r1 = __builtin_amdgcn_permlane32_swap(plo1, phi1, false, false); \
      union { uint u[4]; bf16x8 v; } f_; \
      f_.u[0] = r0.x; f_.u[1] = r1.x; f_.u[2] = r0.y; f_.u[3] = r1.y; \
      pb1 = f_.v; \
    } \
    __builtin_amdgcn_s_setprio(1); \
    A0 = __builtin_amdgcn_mfma_f32_32x32x16_bf16(v0, pb0, A0, 0, 0, 0); \
    A1 = __builtin_amdgcn_mfma_f32_32x32x16_bf16(v1, pb0, A1, 0, 0, 0); \
    A0 = __builtin_amdgcn_mfma_f32_32x32x16_bf16(v2, pb1, A0, 0, 0, 0); \
    A1 = __builtin_amdgcn_mfma_f32_32x32x16_bf16(v3, pb1, A1, 0, 0, 0); \
    __builtin_amdgcn_s_setprio(0); \
  } while (0)

  #pragma unroll 1
  for (int t = 0; t < 32; ++t) {
    // ---- 8 coalesced fragment loads, shared by BOTH q-tiles ----
    bf16x8 k0 = *(const bf16x8*)(kb);
    bf16x8 k1 = *(const bf16x8*)(kb + 512);
    bf16x8 k2 = *(const bf16x8*)(kb + 1024);
    bf16x8 k3 = *(const bf16x8*)(kb + 1536);
    bf16x8 v0 = *(const bf16x8*)(vb);
    bf16x8 v1 = *(const bf16x8*)(vb + 256);
    bf16x8 v2 = *(const bf16x8*)(vb + 1024);
    bf16x8 v3 = *(const bf16x8*)(vb + 1280);
    kb += 2048; vb += 2048;

    TILE(qfA, accA0, accA1, lA);
    TILE(qfB, accB0, accB1, lB);
  }
  #undef TILE

  // ---- 4-way merge of kv-quarter partials (shared implicit m=0) ----
  float lAm = lA + __shfl_xor(lA, 32);
  float lBm = lB + __shfl_xor(lB, 32);

  if (w != 0) {
    float* p = &cmb[w - 1][lane][0];
    #pragma unroll
    for (int i = 0; i < 16; ++i) {
      p[i]      = accA0[i];
      p[16 + i] = accA1[i];
      p[32 + i] = accB0[i];
      p[48 + i] = accB1[i];
    }
    p[64] = lAm;
    p[65] = lBm;
  }
  __syncthreads();
  if (w == 0) {
    float lsA = lAm, lsB = lBm;
    #pragma unroll
    for (int q = 0; q < 3; ++q) { lsA += cmb[q][lane][64]; lsB += cmb[q][lane][65]; }
    const float invA = 1.0f / lsA;
    const float invB = 1.0f / lsB;
    const size_t rowA = (((size_t)b << 12) + qw + r32) << 6;
    const size_t rowB = (((size_t)b << 12) + qw + 32 + r32) << 6;
    #pragma unroll
    for (int g = 0; g < 4; ++g) {
      f32x4 oA, oB;
      #pragma unroll
      for (int i = 0; i < 4; ++i) {
        float vA0 = accA0[4*g + i], vB0 = accB0[4*g + i];
        #pragma unroll
        for (int q = 0; q < 3; ++q) {
          vA0 += cmb[q][lane][4*g + i];
          vB0 += cmb[q][lane][32 + 4*g + i];
        }
        oA[i] = vA0 * invA;
        oB[i] = vB0 * invB;
      }
      *(f32x4*)(out + rowA + (g << 3) + (h << 2)) = oA;
      *(f32x4*)(out + rowB + (g << 3) + (h << 2)) = oB;
    }
    #pragma unroll
    for (int g = 0; g < 4; ++g) {
      f32x4 oA, oB;
      #pragma unroll
      for (int i = 0; i < 4; ++i) {
        float vA1 = accA1[4*g + i], vB1 = accB1[4*g + i];
        #pragma unroll
        for (int q = 0; q < 3; ++q) {
          vA1 += cmb[q][lane][16 + 4*g + i];
          vB1 += cmb[q][lane][48 + 4*g + i];
        }
        oA[i] = vA1 * invA;
        oB[i] = vB1 * invB;
      }
      *(f32x4*)(out + rowA + 32 + (g << 3) + (h << 2)) = oA;
      *(f32x4*)(out + rowB + 32 + (g << 3) + (h << 2)) = oB;
    }
  }
}

extern "C" void kernel_launch(void* const* d_in, const int* in_sizes, int n_in,
                              void* d_out, int out_size, void* d_ws, size_t ws_size,
                              hipStream_t stream) {
  (void)in_sizes; (void)n_in; (void)out_size; (void)ws_size;
  const float* x  = (const float*)d_in[0];
  const float* Wq = (const float*)d_in[1];
  const float* bq = (const float*)d_in[2];
  const float* Wk = (const float*)d_in[3];
  const float* bk = (const float*)d_in[4];
  const float* Wv = (const float*)d_in[5];
  const float* bv = (const float*)d_in[6];
  float* out = (float*)d_out;

  const size_t SZ = (size_t)B_ * N_ * 64;          // 2,097,152 elems (4 MB)
  ushort* Qb = (ushort*)d_ws;
  ushort* KF = Qb + SZ;
  ushort* VF = KF + SZ;

  proj_kernel<<<dim3(256, 3), dim3(256), 0, stream>>>(x, Wq, bq, Wk, bk, Wv, bv,
                                                      Qb, KF, VF);
  flash_kernel<<<dim3(512), dim3(256), 0, stream>>>(Qb, KF, VF, out);
}